// Round 10
// baseline (43.007 us; speedup 1.0000x reference)
//
#include <hip/hip_runtime.h>

// NNLoss: min over 5x5 shifted neighborhoods of channel-summed L1 distance,
// then global mean. B=16, C=3, H=W=512, fp32.
// R10: persistent blocks (2/CU), 4 vertical 128x16 tiles per block,
// double-buffered LDS staged via __builtin_amdgcn_global_load_lds (16B,
// per-lane clamped global src, linear LDS dest). One vmcnt(0)+barrier per
// tile: next tile's loads are in flight under current tile's compute.
// PADV borders via tiny post-stage fixup (uniform branches). GW=148 for
// bank spread. __launch_bounds__(512,2) -> 128-reg cap (cap = 256/arg).

#define PADV (-10000.0f)

constexpr int Bn = 16, Cn = 3, Hn = 512, Wn = 512;
constexpr long PLANE = (long)Hn * Wn;                  // 262144

constexpr int TW = 128, TH = 16;
constexpr int F4ROW = 37;                              // float4 staged per row
constexpr int GW = 4 * F4ROW;                          // 148 floats per row
constexpr int GH = TH + 4;                             // 20 rows: h0-2..h0+17
constexpr int BLOCK = 512;
constexpr int TPB = 4;                                 // tiles per block
constexpr int F4T = Cn * GH * F4ROW;                   // 2220 float4 per tile
constexpr int NBLOCKS = Bn * (Wn / TW) * (Hn / TH / TPB);  // 512

typedef const unsigned int __attribute__((address_space(1)))* gas1_t;
typedef unsigned int __attribute__((address_space(3)))* las3_t;

__global__ __launch_bounds__(BLOCK, 2) void nnloss_main(
    const float* __restrict__ pred, const float* __restrict__ gt,
    float* __restrict__ partial) {
  const int bid = blockIdx.x;
  const int tw = bid & 3;
  const int thg = (bid >> 2) & 7;
  const int b = bid >> 5;
  const int w0 = tw * TW;
  const int h0base = thg * (TH * TPB);

  __shared__ __align__(16) float tile[2][Cn][GH][GW];  // 71,040 B

  const float* gb = gt + (long)b * Cn * PLANE;
  const float* pb = pred + (long)b * Cn * PLANE;

  const int ty = threadIdx.x >> 5;                     // 16 rows
  const int tx = threadIdx.x & 31;                     // 32 strips of 4 px

  // ---- async stage: global -> LDS direct, clamped source addresses ----
  auto stage = [&](int h0, int nb) {
    float* dst0 = &tile[nb][0][0][0];
#pragma unroll
    for (int m = 0; m < 5; ++m) {
      const int idx = threadIdx.x + m * BLOCK;
      if (idx < F4T) {
        const int c = idx / (GH * F4ROW);
        const int rem = idx - c * (GH * F4ROW);
        const int r = rem / F4ROW;
        const int k = rem - r * F4ROW;
        const int gh = min(max(h0 - 2 + r, 0), Hn - 1);
        const int gc = min(max(w0 - 4 + 4 * k, 0), Wn - 4);
        const float* src = gb + (long)c * PLANE + (long)gh * Wn + gc;
        float* dst = dst0 + 4 * idx;
        __builtin_amdgcn_global_load_lds((gas1_t)(const void*)src,
                                         (las3_t)(void*)dst, 16, 0, 0);
      }
    }
  };

  // ---- PADV fixups for image borders (uniform branches; cheap) ----
  auto fixup = [&](int h0, int nb) {
    if (h0 == 0) {                                     // rows 0,1 = gh -2,-1
      for (int i = threadIdx.x; i < Cn * 2 * F4ROW; i += BLOCK) {
        const int c = i / (2 * F4ROW);
        const int rem = i - c * (2 * F4ROW);
        const int r = rem / F4ROW;
        const int k = rem - r * F4ROW;
        *(float4*)&tile[nb][c][r][4 * k] = make_float4(PADV, PADV, PADV, PADV);
      }
    }
    if (h0 == Hn - TH) {                               // rows 18,19 = gh 512,513
      for (int i = threadIdx.x; i < Cn * 2 * F4ROW; i += BLOCK) {
        const int c = i / (2 * F4ROW);
        const int rem = i - c * (2 * F4ROW);
        const int r = 18 + rem / F4ROW;
        const int k = rem % F4ROW;
        *(float4*)&tile[nb][c][r][4 * k] = make_float4(PADV, PADV, PADV, PADV);
      }
    }
    if (tw == 0 && threadIdx.x < Cn * GH) {            // L2,L3 = cols -2,-1
      const int c = threadIdx.x / GH;
      const int r = threadIdx.x - c * GH;
      tile[nb][c][r][2] = PADV;
      tile[nb][c][r][3] = PADV;
    }
    if (tw == 3 && threadIdx.x < Cn * GH) {            // L132,133 = cols 512,513
      const int c = threadIdx.x / GH;
      const int r = threadIdx.x - c * GH;
      tile[nb][c][r][132] = PADV;
      tile[nb][c][r][133] = PADV;
    }
  };

  auto pred_load = [&](int h0, float (&p)[Cn][4]) {
    const float* pp = pb + (long)(h0 + ty) * Wn + (w0 + 4 * tx);
#pragma unroll
    for (int c = 0; c < Cn; ++c) {
      const float4 v = *(const float4*)(pp + (long)c * PLANE);
      p[c][0] = v.x; p[c][1] = v.y; p[c][2] = v.z; p[c][3] = v.w;
    }
  };

  // window: pixel q, shift dj -> LDS col 4tx + q + dj + 2 -> g[q+dj+2]
  auto compute = [&](const float (&p)[Cn][4], int cb) -> float {
    float mm[4] = {3.0e38f, 3.0e38f, 3.0e38f, 3.0e38f};
#pragma unroll
    for (int di = 0; di < 5; ++di) {
      float s[5][4];
#pragma unroll
      for (int c = 0; c < Cn; ++c) {
        const float* base = &tile[cb][c][ty + di][4 * tx];
        const float4 A = *(const float4*)(base);
        const float4 Bq = *(const float4*)(base + 4);
        const float2 Cq = *(const float2*)(base + 8);
        float g[10];
        g[0] = A.x;  g[1] = A.y;  g[2] = A.z;  g[3] = A.w;
        g[4] = Bq.x; g[5] = Bq.y; g[6] = Bq.z; g[7] = Bq.w;
        g[8] = Cq.x; g[9] = Cq.y;
        if (c == 0) {
#pragma unroll
          for (int dj = 0; dj < 5; ++dj)
#pragma unroll
            for (int q = 0; q < 4; ++q)
              s[dj][q] = fabsf(g[q + dj + 2] - p[0][q]);
        } else {
#pragma unroll
          for (int dj = 0; dj < 5; ++dj)
#pragma unroll
            for (int q = 0; q < 4; ++q)
              s[dj][q] += fabsf(g[q + dj + 2] - p[c][q]);
        }
      }
#pragma unroll
      for (int q = 0; q < 4; ++q) {
        const float t1 = fminf(fminf(s[0][q], s[1][q]), s[2][q]);  // v_min3
        const float t2 = fminf(fminf(t1, s[3][q]), s[4][q]);       // v_min3
        mm[q] = fminf(mm[q], t2);
      }
    }
    return (mm[0] + mm[1]) + (mm[2] + mm[3]);
  };

  // ---- pipelined tile loop ----
  float pcur[Cn][4], pnext[Cn][4];

  stage(h0base, 0);
  pred_load(h0base, pcur);
  asm volatile("s_waitcnt vmcnt(0)" ::: "memory");
  __syncthreads();
  fixup(h0base, 0);
  __syncthreads();

  float vacc = 0.f;
#pragma unroll
  for (int t = 0; t < TPB; ++t) {
    const int h0 = h0base + t * TH;
    if (t < TPB - 1) {
      stage(h0 + TH, (t + 1) & 1);                     // async, in flight
      pred_load(h0 + TH, pnext);
    }
    vacc += compute(pcur, t & 1);
    if (t < TPB - 1) {
      asm volatile("s_waitcnt vmcnt(0)" ::: "memory"); // stage landed
      __syncthreads();                                 // all waves done
      fixup(h0 + TH, (t + 1) & 1);
#pragma unroll
      for (int c = 0; c < Cn; ++c)
#pragma unroll
        for (int q = 0; q < 4; ++q) pcur[c][q] = pnext[c][q];
      __syncthreads();                                 // fixup visible
    }
  }

  // ---- block reduction ----
#pragma unroll
  for (int off = 32; off > 0; off >>= 1) vacc += __shfl_down(vacc, off, 64);
  __shared__ float wsum[BLOCK / 64];
  const int lane = threadIdx.x & 63;
  const int wid = threadIdx.x >> 6;
  if (lane == 0) wsum[wid] = vacc;
  __syncthreads();
  if (threadIdx.x == 0) {
    float tsum = 0.f;
#pragma unroll
    for (int i = 0; i < BLOCK / 64; ++i) tsum += wsum[i];
    partial[bid] = tsum;
  }
}

__global__ __launch_bounds__(256) void nnloss_reduce(
    const float* __restrict__ partial, float* __restrict__ out) {
  double acc = 0.0;
  for (int i = threadIdx.x; i < NBLOCKS; i += 256) acc += (double)partial[i];
#pragma unroll
  for (int off = 32; off > 0; off >>= 1) acc += __shfl_down(acc, off, 64);
  __shared__ double sd[4];
  const int lane = threadIdx.x & 63;
  const int wid = threadIdx.x >> 6;
  if (lane == 0) sd[wid] = acc;
  __syncthreads();
  if (threadIdx.x == 0) {
    const double tot = (sd[0] + sd[1]) + (sd[2] + sd[3]);
    out[0] = (float)(tot / ((double)Bn * Hn * Wn));
  }
}

extern "C" void kernel_launch(void* const* d_in, const int* in_sizes, int n_in,
                              void* d_out, int out_size, void* d_ws, size_t ws_size,
                              hipStream_t stream) {
  const float* pred = (const float*)d_in[0];
  const float* gt = (const float*)d_in[1];
  // d_in[2], d_in[3] are nh=5, nw=5 (hard-coded)
  float* out = (float*)d_out;
  float* partial = (float*)d_ws;  // 512 floats

  nnloss_main<<<NBLOCKS, BLOCK, 0, stream>>>(pred, gt, partial);
  nnloss_reduce<<<1, 256, 0, stream>>>(partial, out);
}

// Round 11
// 35.134 us; speedup vs baseline: 1.2241x; 1.2241x over previous
//
#include <hip/hip_runtime.h>

// NNLoss: min over 5x5 shifted neighborhoods of channel-summed L1 distance,
// then global mean. B=16, C=3, H=W=512, fp32.
// R11: test the memory-contiguity hypothesis. Wide tiles (TW=256): staged
// runs are 1056 B contiguous; adjacent bands on the same XCD (bijective
// swizzle) stream adjacent rows. GW=268 (≡12 mod 32, conflict-free class).
// 512 thr, 8 px/thread, LDS 64.3 KB -> 2 resident blocks/CU for natural
// cross-block stage/compute overlap. Gather-then-write staging, no halo
// pass (unconditional per-component clamp+select). Cap 128 via (512,2).

#define PADV (-10000.0f)

constexpr int Bn = 16, Cn = 3, Hn = 512, Wn = 512;
constexpr long PLANE = (long)Hn * Wn;                  // 262144

constexpr int TW = 256, TH = 16;
constexpr int GW = 268;                                // 268 % 32 == 12
constexpr int GH = TH + 4;                             // 20 rows: h0-2..h0+17
constexpr int F4ROW = 66;                              // 264 floats: w0-4..w0+259
constexpr int F4T = Cn * GH * F4ROW;                   // 3960
constexpr int BLOCK = 512;
constexpr int SR = 8;                                  // ceil(3960/512)
constexpr int NBLOCKS = Bn * 2 * (Hn / TH);            // 1024

__global__ __launch_bounds__(BLOCK, 2) void nnloss_main(
    const float* __restrict__ pred, const float* __restrict__ gt,
    float* __restrict__ partial) {
  // bijective XCD swizzle (1024 % 8 == 0): each XCD gets contiguous wg range;
  // wg order: band fastest -> vertical neighbors co-located on an XCD.
  const int wg = (blockIdx.x & 7) * (NBLOCKS / 8) + (blockIdx.x >> 3);
  const int band = wg & 31;
  const int tw = (wg >> 5) & 1;
  const int b = wg >> 6;
  const int w0 = tw * TW;
  const int h0 = band * TH;

  __shared__ __align__(16) float tile[Cn][GH][GW];     // 64,320 B

  const float* gb = gt + (long)b * Cn * PLANE;
  const float* pb = pred + (long)b * Cn * PLANE;

  // ---- stage: gather all loads (in flight together), then write ----
  float4 sv[SR];
#pragma unroll
  for (int m = 0; m < SR; ++m) {
    const int idx = threadIdx.x + m * BLOCK;
    if (idx < F4T) {
      const int c = idx / (GH * F4ROW);
      const int rem = idx - c * (GH * F4ROW);
      const int r = rem / F4ROW;
      const int k = rem - r * F4ROW;
      const int ghc = min(max(h0 - 2 + r, 0), Hn - 1);
      const int gcc = min(max(w0 - 4 + 4 * k, 0), Wn - 4);
      sv[m] = *(const float4*)(gb + (long)c * PLANE + (long)ghc * Wn + gcc);
    }
  }

  // pred loads issued before the barrier too (independent of LDS)
  const int tx = threadIdx.x & 31;                     // 32 strips of 8 px
  const int ty = threadIdx.x >> 5;                     // 16 rows
  float p[Cn][8];
  {
    const float* pp = pb + (long)(h0 + ty) * Wn + (w0 + 8 * tx);
#pragma unroll
    for (int c = 0; c < Cn; ++c) {
      const float4 v0 = *(const float4*)(pp + (long)c * PLANE);
      const float4 v1 = *(const float4*)(pp + (long)c * PLANE + 4);
      p[c][0] = v0.x; p[c][1] = v0.y; p[c][2] = v0.z; p[c][3] = v0.w;
      p[c][4] = v1.x; p[c][5] = v1.y; p[c][6] = v1.z; p[c][7] = v1.w;
    }
  }

#pragma unroll
  for (int m = 0; m < SR; ++m) {
    const int idx = threadIdx.x + m * BLOCK;
    if (idx < F4T) {
      const int c = idx / (GH * F4ROW);
      const int rem = idx - c * (GH * F4ROW);
      const int r = rem / F4ROW;
      const int k = rem - r * F4ROW;
      const int gh = h0 - 2 + r;
      const int gc0 = w0 - 4 + 4 * k;
      const bool rb = (gh < 0) || (gh >= Hn);
      float4 v = sv[m];
      v.x = (rb || (gc0 + 0) < 0 || (gc0 + 0) >= Wn) ? PADV : v.x;
      v.y = (rb || (gc0 + 1) < 0 || (gc0 + 1) >= Wn) ? PADV : v.y;
      v.z = (rb || (gc0 + 2) < 0 || (gc0 + 2) >= Wn) ? PADV : v.z;
      v.w = (rb || (gc0 + 3) < 0 || (gc0 + 3) >= Wn) ? PADV : v.w;
      *(float4*)&tile[c][r][4 * k] = v;
    }
  }
  __syncthreads();

  // ---- compute: 8 px/thread; window cols L = 8tx+2 .. 8tx+13 ----
  float m8[8];
#pragma unroll
  for (int q = 0; q < 8; ++q) m8[q] = 3.0e38f;

#pragma unroll
  for (int di = 0; di < 5; ++di) {
    float s[5][8];
    float g[14];
#pragma unroll
    for (int c = 0; c < Cn; ++c) {
      const float* base = &tile[c][ty + di][8 * tx];
      const float2 e0 = *(const float2*)(base + 2);
      const float4 A = *(const float4*)(base + 4);
      const float4 B2 = *(const float4*)(base + 8);
      const float2 e1 = *(const float2*)(base + 12);
      g[2] = e0.x;  g[3] = e0.y;
      g[4] = A.x;   g[5] = A.y;   g[6] = A.z;   g[7] = A.w;
      g[8] = B2.x;  g[9] = B2.y;  g[10] = B2.z; g[11] = B2.w;
      g[12] = e1.x; g[13] = e1.y;
      if (c == 0) {
#pragma unroll
        for (int dj = 0; dj < 5; ++dj)
#pragma unroll
          for (int q = 0; q < 8; ++q)
            s[dj][q] = fabsf(g[q + dj + 2] - p[0][q]);
      } else {
#pragma unroll
        for (int dj = 0; dj < 5; ++dj)
#pragma unroll
          for (int q = 0; q < 8; ++q)
            s[dj][q] += fabsf(g[q + dj + 2] - p[c][q]);
      }
    }
#pragma unroll
    for (int q = 0; q < 8; ++q) {
      const float t1 = fminf(fminf(s[0][q], s[1][q]), s[2][q]);   // v_min3
      const float t2 = fminf(fminf(t1, s[3][q]), s[4][q]);        // v_min3
      m8[q] = fminf(m8[q], t2);
    }
  }

  float v = ((m8[0] + m8[1]) + (m8[2] + m8[3])) +
            ((m8[4] + m8[5]) + (m8[6] + m8[7]));

  // ---- block reduction ----
#pragma unroll
  for (int off = 32; off > 0; off >>= 1) v += __shfl_down(v, off, 64);
  __shared__ float wsum[BLOCK / 64];
  const int lane = threadIdx.x & 63;
  const int wid = threadIdx.x >> 6;
  if (lane == 0) wsum[wid] = v;
  __syncthreads();
  if (threadIdx.x == 0) {
    float t = 0.f;
#pragma unroll
    for (int i = 0; i < BLOCK / 64; ++i) t += wsum[i];
    partial[blockIdx.x] = t;
  }
}

__global__ __launch_bounds__(256) void nnloss_reduce(
    const float* __restrict__ partial, float* __restrict__ out) {
  double acc = 0.0;
  for (int i = threadIdx.x; i < NBLOCKS; i += 256) acc += (double)partial[i];
#pragma unroll
  for (int off = 32; off > 0; off >>= 1) acc += __shfl_down(acc, off, 64);
  __shared__ double sd[4];
  const int lane = threadIdx.x & 63;
  const int wid = threadIdx.x >> 6;
  if (lane == 0) sd[wid] = acc;
  __syncthreads();
  if (threadIdx.x == 0) {
    const double tot = (sd[0] + sd[1]) + (sd[2] + sd[3]);
    out[0] = (float)(tot / ((double)Bn * Hn * Wn));
  }
}

extern "C" void kernel_launch(void* const* d_in, const int* in_sizes, int n_in,
                              void* d_out, int out_size, void* d_ws, size_t ws_size,
                              hipStream_t stream) {
  const float* pred = (const float*)d_in[0];
  const float* gt = (const float*)d_in[1];
  // d_in[2], d_in[3] are nh=5, nw=5 (hard-coded)
  float* out = (float*)d_out;
  float* partial = (float*)d_ws;  // 1024 floats = 4 KB

  nnloss_main<<<NBLOCKS, BLOCK, 0, stream>>>(pred, gt, partial);
  nnloss_reduce<<<1, 256, 0, stream>>>(partial, out);
}